// Round 1
// baseline (4326.838 us; speedup 1.0000x reference)
//
#include <hip/hip_runtime.h>
#include <cstdint>
#include <cstddef>

#define NBATCH 32
#define NAGENT 100
#define NDIM   10000
#define HID    256
#define NHEAD  4
#define NOUT   10000
#define NFREQ  16
#define EMAX   100
#define NBA    3200                        // NBATCH * NAGENT
#define TWO_PI 6.283185307179586476925f

// ---------------------------------------------------------------------------
// Stage 1: per-(b,a) stream compaction of nonzeros (ascending flat index),
// truncated to EMAX. One wave per (b,a). Matches stable argsort order.
// ---------------------------------------------------------------------------
__global__ __launch_bounds__(64) void k_extract(const float* __restrict__ x,
                                                int* __restrict__ idxb,
                                                float* __restrict__ valb,
                                                int* __restrict__ nvalid)
{
    const int ba = blockIdx.x;
    const float* xr = x + (size_t)ba * NDIM;
    const int lane = threadIdx.x;
    int base = 0;
    for (int c0 = 0; c0 < NDIM; c0 += 64) {
        int i = c0 + lane;
        float v = (i < NDIM) ? xr[i] : 0.0f;
        unsigned long long m = __ballot(v != 0.0f);
        if (v != 0.0f) {
            int p = base + __popcll(m & ((1ull << lane) - 1ull));
            if (p < EMAX) {
                idxb[(size_t)ba * EMAX + p] = i;
                valb[(size_t)ba * EMAX + p] = v;
            }
        }
        base += __popcll(m);
        if (base >= EMAX) break;           // uniform across wave
    }
    if (lane == 0) nvalid[ba] = base < EMAX ? base : EMAX;
}

// ---------------------------------------------------------------------------
// Stage 2: fused entry encoder. Tile = 16 entries/block, full 256-wide output.
// feat(33) -> swish(W1)(256) in LDS -> @W2.T + b2 (or pad_token if invalid).
// Writes e laid out as Flat[ba][slot*256 + j]  (= e[(g)*256 + j], g=ba*100+slot)
// LDS ~56 KB -> 2 blocks/CU.
// ---------------------------------------------------------------------------
__global__ __launch_bounds__(256) void k_encode(
    const int* __restrict__ idxb, const float* __restrict__ valb,
    const int* __restrict__ nvalid, const float* __restrict__ fourB,
    const float* __restrict__ W1, const float* __restrict__ b1,
    const float* __restrict__ W2, const float* __restrict__ b2,
    const float* __restrict__ pad, float* __restrict__ e)
{
    __shared__ float s_feat[16][36];
    __shared__ float s_g1[16][257];
    __shared__ float s_w[8448];            // phase1: W1 (256x33); phase2: W2 chunk (32x256 transposed)
    __shared__ float s_b1[256];
    __shared__ float s_b2[256];
    __shared__ float s_pad[256];
    __shared__ int   s_idx[16];
    __shared__ int   s_valid[16];

    const int t  = threadIdx.x;
    const int g0 = blockIdx.x * 16;

    if (t < 16) {
        int g = g0 + t;
        int ba = g / 100, slot = g - ba * 100;
        int valid = (slot < nvalid[ba]) ? 1 : 0;
        s_valid[t]   = valid;
        s_idx[t]     = valid ? idxb[g] : 0;
        s_feat[t][0] = valid ? valb[g] : 0.0f;
    }
    s_b1[t]  = b1[t];
    s_b2[t]  = b2[t];
    s_pad[t] = pad[t];
    for (int i = t; i < 8448; i += 256) s_w[i] = W1[i];
    __syncthreads();

    {   // Fourier features: 16 entries x 16 freqs = 256 work items
        int ent = t >> 4, f = t & 15;
        float sv = 0.0f, cv = 0.0f;
        if (s_valid[ent]) {
            int id = s_idx[ent];
            float row = (float)(id / 100);
            float col = (float)(id % 100);
            float pr = TWO_PI * (row * fourB[2 * f] + col * fourB[2 * f + 1]);
            sv = sinf(pr); cv = cosf(pr);
        }
        s_feat[ent][1 + f]  = sv;
        s_feat[ent][17 + f] = cv;
    }
    __syncthreads();

    // layer 1: thread t computes g1[ent][t] for all 16 entries
    {
        const float* wr = &s_w[t * 33];
        for (int ent = 0; ent < 16; ++ent) {
            float a = s_b1[t];
            #pragma unroll
            for (int c = 0; c < 33; ++c) a += s_feat[ent][c] * wr[c];
            s_g1[ent][t] = a / (1.0f + expf(-a));      // swish
        }
    }

    // layer 2: e[ent][j] = sum_k g1[ent][k] * W2[j][k]
    const int tj = t & 31, te = t >> 5;
    const int j0 = tj * 8, ent0 = te * 2;
    float acc[2][8];
    #pragma unroll
    for (int i = 0; i < 2; ++i)
        #pragma unroll
        for (int j = 0; j < 8; ++j) acc[i][j] = 0.0f;

    for (int kc = 0; kc < 8; ++kc) {
        __syncthreads();                    // previous s_w consumers done
        {
            const float4* src = (const float4*)(W2 + (size_t)t * 256 + kc * 32);
            #pragma unroll
            for (int q = 0; q < 8; ++q) {
                float4 v = src[q];
                int cb = q * 4;
                s_w[(cb + 0) * 256 + t] = v.x;
                s_w[(cb + 1) * 256 + t] = v.y;
                s_w[(cb + 2) * 256 + t] = v.z;
                s_w[(cb + 3) * 256 + t] = v.w;
            }
        }
        __syncthreads();
        #pragma unroll 8
        for (int c = 0; c < 32; ++c) {
            int k = kc * 32 + c;
            float a0 = s_g1[ent0][k];
            float a1 = s_g1[ent0 + 1][k];
            const float* wr = &s_w[c * 256 + j0];
            float w[8];
            *(float4*)&w[0] = *(const float4*)wr;
            *(float4*)&w[4] = *(const float4*)(wr + 4);
            #pragma unroll
            for (int j = 0; j < 8; ++j) {
                acc[0][j] += a0 * w[j];
                acc[1][j] += a1 * w[j];
            }
        }
    }

    #pragma unroll
    for (int i = 0; i < 2; ++i) {
        int ent = ent0 + i;
        int g = g0 + ent;
        int valid = s_valid[ent];
        float o[8];
        #pragma unroll
        for (int j = 0; j < 8; ++j)
            o[j] = valid ? (acc[i][j] + s_b2[j0 + j]) : s_pad[j0 + j];
        float* dst = e + (size_t)g * 256 + j0;
        *(float4*)(dst)     = make_float4(o[0], o[1], o[2], o[3]);
        *(float4*)(dst + 4) = make_float4(o[4], o[5], o[6], o[7]);
    }
}

// ---------------------------------------------------------------------------
// Generic fp32 GEMM: C = act(A @ W^T + bias).  A:[M,K] row-major, W:[N,K]
// row-major (= torch-style [out,in] weights). 128x128 tile, BK=16, 8x8 micro,
// 256 threads. Requires M%128==0, K%16==0. N-edge guarded.
// SPLITK: blockIdx.z = k-chunk, writes partial C (no bias/act).
// Else:   blockIdx.z = batch index with strides sA/sW/sBias/sC (elements).
// Global loads for tile k+1 issued before compute on tile k (latency hiding).
// ---------------------------------------------------------------------------
template<int ACT, bool SPLITK>
__global__ __launch_bounds__(256) void k_gemm128(
    const float* __restrict__ A, const float* __restrict__ W,
    const float* __restrict__ bias, float* __restrict__ C,
    int M, int N, int K,
    long long sA, long long sW, long long sBias, long long sC,
    int kChunk)
{
    __shared__ float As[16][132];
    __shared__ float Ws[16][132];
    const int t = threadIdx.x;
    const int z = blockIdx.z;
    int k0s = 0, k0e = K;
    if (SPLITK) {
        k0s = z * kChunk;
        int ke = k0s + kChunk; k0e = ke < K ? ke : K;
        C += (size_t)z * M * N;
    } else {
        A += (size_t)z * sA;
        W += (size_t)z * sW;
        C += (size_t)z * sC;
        if (bias) bias += (size_t)z * sBias;
    }
    const int bm = blockIdx.y * 128, bn = blockIdx.x * 128;
    const int m0 = (t & 15) * 8, n0 = (t >> 4) * 8;

    float acc[8][8];
    #pragma unroll
    for (int i = 0; i < 8; ++i)
        #pragma unroll
        for (int j = 0; j < 8; ++j) acc[i][j] = 0.0f;

    float4 av[2], wv[2];
    // preload first tile
    #pragma unroll
    for (int i = 0; i < 2; ++i) {
        int id = i * 256 + t;
        int row = id >> 2;
        int kg = (id & 3) << 2;
        av[i] = *(const float4*)(A + (size_t)(bm + row) * K + k0s + kg);
        int nr = bn + row;
        wv[i] = (nr < N) ? *(const float4*)(W + (size_t)nr * K + k0s + kg)
                         : make_float4(0.f, 0.f, 0.f, 0.f);
    }

    for (int k0 = k0s; k0 < k0e; k0 += 16) {
        __syncthreads();
        #pragma unroll
        for (int i = 0; i < 2; ++i) {
            int id = i * 256 + t;
            int row = id >> 2;
            int kg = (id & 3) << 2;
            As[kg + 0][row] = av[i].x; As[kg + 1][row] = av[i].y;
            As[kg + 2][row] = av[i].z; As[kg + 3][row] = av[i].w;
            Ws[kg + 0][row] = wv[i].x; Ws[kg + 1][row] = wv[i].y;
            Ws[kg + 2][row] = wv[i].z; Ws[kg + 3][row] = wv[i].w;
        }
        __syncthreads();
        int kn = k0 + 16;
        if (kn < k0e) {   // prefetch next tile while computing this one
            #pragma unroll
            for (int i = 0; i < 2; ++i) {
                int id = i * 256 + t;
                int row = id >> 2;
                int kg = (id & 3) << 2;
                av[i] = *(const float4*)(A + (size_t)(bm + row) * K + kn + kg);
                int nr = bn + row;
                wv[i] = (nr < N) ? *(const float4*)(W + (size_t)nr * K + kn + kg)
                                 : make_float4(0.f, 0.f, 0.f, 0.f);
            }
        }
        #pragma unroll
        for (int kk = 0; kk < 16; ++kk) {
            float a[8], w[8];
            *(float4*)&a[0] = *(const float4*)&As[kk][m0];
            *(float4*)&a[4] = *(const float4*)&As[kk][m0 + 4];
            *(float4*)&w[0] = *(const float4*)&Ws[kk][n0];
            *(float4*)&w[4] = *(const float4*)&Ws[kk][n0 + 4];
            #pragma unroll
            for (int i = 0; i < 8; ++i)
                #pragma unroll
                for (int j = 0; j < 8; ++j)
                    acc[i][j] += a[i] * w[j];
        }
    }

    #pragma unroll
    for (int i = 0; i < 8; ++i) {
        int row = bm + m0 + i;
        float* crow = C + (size_t)row * N;
        #pragma unroll
        for (int j = 0; j < 8; ++j) {
            int n = bn + n0 + j;
            if (n < N) {
                float v = acc[i][j];
                if (!SPLITK && bias) v += bias[n];
                if (ACT == 1) v = v / (1.0f + expf(-v));   // swish
                crow[n] = v;
            }
        }
    }
}

// ---------------------------------------------------------------------------
// Split-K reduce for the compression GEMM: h1s = swish(sum_z part + comp_b1)
// ---------------------------------------------------------------------------
__global__ __launch_bounds__(256) void k_g3red(const float* __restrict__ part,
                                               const float* __restrict__ bias,
                                               float* __restrict__ outp)
{
    const int i4 = (blockIdx.x * 256 + threadIdx.x) * 4;
    const size_t S = (size_t)NBA * 512;
    float4 a = *(const float4*)(part + i4);
    float4 b = *(const float4*)(part + S + i4);
    float4 c = *(const float4*)(part + 2 * S + i4);
    float4 d = *(const float4*)(part + 3 * S + i4);
    float4 bi = *(const float4*)(bias + (i4 & 511));
    float r0 = a.x + b.x + c.x + d.x + bi.x;
    float r1 = a.y + b.y + c.y + d.y + bi.y;
    float r2 = a.z + b.z + c.z + d.z + bi.z;
    float r3 = a.w + b.w + c.w + d.w + bi.w;
    float4 o;
    o.x = r0 / (1.0f + expf(-r0));
    o.y = r1 / (1.0f + expf(-r1));
    o.z = r2 / (1.0f + expf(-r2));
    o.w = r3 / (1.0f + expf(-r3));
    *(float4*)(outp + i4) = o;
}

// ---------------------------------------------------------------------------
// Fused attention: per (half-of-rows, b, head): S = QK^T/16 + conn,
// softmax, Hm = alpha @ V, write swish(Hm). K/V staged channel-major in LDS
// ([256][101] -> conflict-free reads both phases). LDS ~125 KB.
// ---------------------------------------------------------------------------
__global__ __launch_bounds__(256) void k_attn(
    const float* __restrict__ Qb, const float* __restrict__ Kb,
    const float* __restrict__ Vb, const float* __restrict__ conn,
    float* __restrict__ sHm)
{
    __shared__ float sKV[256][101];
    __shared__ float sAl[50][100];
    __shared__ float sQ[2][256];
    __shared__ float sRed[2][2];

    const int t = threadIdx.x;
    const int half = blockIdx.x, b = blockIdx.y, n = blockIdx.z;
    const size_t base = ((size_t)n * NBA + b * 100) * 256;

    const float* Kp = Kb + base;
    for (int r = 0; r < 100; ++r) sKV[t][r] = Kp[(size_t)r * 256 + t];
    __syncthreads();

    const float* Qp = Qb + base;
    const int pair = t >> 7, tt = t & 127, lane = t & 63, wvi = t >> 6;

    for (int rr = 0; rr < 25; ++rr) {
        const int row0 = half * 50 + rr * 2;
        const int lr = rr * 2 + pair;
        __syncthreads();
        sQ[0][t] = Qp[(size_t)(row0)*256 + t];
        sQ[1][t] = Qp[(size_t)(row0 + 1) * 256 + t];
        __syncthreads();
        float sc = 0.0f;
        if (tt < 100) {
            const float* qr = sQ[pair];
            float p0 = 0.f, p1 = 0.f, p2 = 0.f, p3 = 0.f;
            #pragma unroll 4
            for (int c = 0; c < 256; c += 4) {
                p0 += qr[c]     * sKV[c][tt];
                p1 += qr[c + 1] * sKV[c + 1][tt];
                p2 += qr[c + 2] * sKV[c + 2][tt];
                p3 += qr[c + 3] * sKV[c + 3][tt];
            }
            sc = ((p0 + p1) + (p2 + p3)) * 0.0625f + conn[(row0 + pair) * 100 + tt];
            sAl[lr][tt] = sc;
        }
        __syncthreads();
        if ((wvi & 1) == 0) {              // waves 0,2 reduce their pair's row
            int p = wvi >> 1;
            int r2 = rr * 2 + p;
            float m = sAl[r2][lane];
            if (lane < 36) m = fmaxf(m, sAl[r2][lane + 64]);
            #pragma unroll
            for (int off = 32; off > 0; off >>= 1)
                m = fmaxf(m, __shfl_down(m, off));
            if (lane == 0) sRed[0][p] = m;
        }
        __syncthreads();
        float ex = 0.0f;
        if (tt < 100) {
            ex = expf(sc - sRed[0][pair]);
            sAl[lr][tt] = ex;
        }
        __syncthreads();
        if ((wvi & 1) == 0) {
            int p = wvi >> 1;
            int r2 = rr * 2 + p;
            float s = sAl[r2][lane];
            if (lane < 36) s += sAl[r2][lane + 64];
            #pragma unroll
            for (int off = 32; off > 0; off >>= 1)
                s += __shfl_down(s, off);
            if (lane == 0) sRed[1][p] = s;
        }
        __syncthreads();
        if (tt < 100) sAl[lr][tt] = ex / sRed[1][pair];
    }
    __syncthreads();

    const float* Vp = Vb + base;
    for (int r = 0; r < 100; ++r) sKV[t][r] = Vp[(size_t)r * 256 + t];
    __syncthreads();

    float* Op = sHm + base;
    for (int rr = 0; rr < 50; ++rr) {
        int row = half * 50 + rr;
        float a = 0.0f;
        #pragma unroll 4
        for (int j = 0; j < 100; ++j) a += sAl[rr][j] * sKV[t][j];
        float sw = a / (1.0f + expf(-a));   // swish fused (fp1 consumes swish(Hm))
        Op[(size_t)row * 256 + t] = sw;
    }
}

// ---------------------------------------------------------------------------
// Per-head layernorm over HID + mean over heads -> new h.
// Block = 256 (wave n handles head n).
// ---------------------------------------------------------------------------
__global__ __launch_bounds__(256) void k_ln_mean(
    const float* __restrict__ t2b, const float* __restrict__ ln_g,
    const float* __restrict__ ln_b, float* __restrict__ h)
{
    __shared__ float so[4][256];
    const int ba = blockIdx.x, t = threadIdx.x;
    const int n = t >> 6, lane = t & 63;
    const float* tr = t2b + ((size_t)n * NBA + ba) * HID;
    float4 v = *(const float4*)(tr + lane * 4);
    float s1 = v.x + v.y + v.z + v.w;
    float s2 = v.x * v.x + v.y * v.y + v.z * v.z + v.w * v.w;
    #pragma unroll
    for (int off = 32; off > 0; off >>= 1) {
        s1 += __shfl_down(s1, off);
        s2 += __shfl_down(s2, off);
    }
    s1 = __shfl(s1, 0);
    s2 = __shfl(s2, 0);
    float m = s1 * (1.0f / 256.0f);
    float var = s2 * (1.0f / 256.0f) - m * m;
    float rstd = 1.0f / sqrtf(var + 1e-5f);
    float4 gv = *(const float4*)(ln_g + n * HID + lane * 4);
    float4 bv = *(const float4*)(ln_b + n * HID + lane * 4);
    float4 o;
    o.x = (v.x - m) * rstd * gv.x + bv.x;
    o.y = (v.y - m) * rstd * gv.y + bv.y;
    o.z = (v.z - m) * rstd * gv.z + bv.z;
    o.w = (v.w - m) * rstd * gv.w + bv.w;
    *(float4*)&so[n][lane * 4] = o;
    __syncthreads();
    h[(size_t)ba * HID + t] = 0.25f * (so[0][t] + so[1][t] + so[2][t] + so[3][t]);
}

// ---------------------------------------------------------------------------
extern "C" void kernel_launch(void* const* d_in, const int* in_sizes, int n_in,
                              void* d_out, int out_size, void* d_ws, size_t ws_size,
                              hipStream_t stream)
{
    const float* x       = (const float*)d_in[0];
    const float* fourB   = (const float*)d_in[1];
    const float* enc_W1  = (const float*)d_in[2];
    const float* enc_b1  = (const float*)d_in[3];
    const float* enc_W2  = (const float*)d_in[4];
    const float* enc_b2  = (const float*)d_in[5];
    const float* pad_tok = (const float*)d_in[6];
    const float* comp_W1 = (const float*)d_in[7];
    const float* comp_b1 = (const float*)d_in[8];
    const float* comp_W2 = (const float*)d_in[9];
    const float* comp_b2 = (const float*)d_in[10];
    const float* conn    = (const float*)d_in[11];
    const float* qW      = (const float*)d_in[12];
    const float* kW      = (const float*)d_in[13];
    const float* vW      = (const float*)d_in[14];
    const float* fpW1    = (const float*)d_in[15];
    const float* fpb1    = (const float*)d_in[16];
    const float* fpW2    = (const float*)d_in[17];
    const float* fpb2    = (const float*)d_in[18];
    const float* ln_g    = (const float*)d_in[19];
    const float* ln_b    = (const float*)d_in[20];
    const float* out_W   = (const float*)d_in[21];
    const float* out_b   = (const float*)d_in[22];
    float* outp = (float*)d_out;

    char* ws = (char*)d_ws;
    size_t off = 0;
    auto alloc = [&](size_t bytes) -> void* {
        void* p = (void*)(ws + off);
        off += (bytes + 255) & ~(size_t)255;
        return p;
    };
    int*   idxb   = (int*)  alloc((size_t)NBA * EMAX * 4);
    float* valb   = (float*)alloc((size_t)NBA * EMAX * 4);
    int*   nval   = (int*)  alloc((size_t)NBA * 4);
    float* e      = (float*)alloc((size_t)NBA * EMAX * HID * 4);   // 327.7 MB
    float* g3part = (float*)alloc((size_t)4 * NBA * 512 * 4);
    float* h1s    = (float*)alloc((size_t)NBA * 512 * 4);
    float* h      = (float*)alloc((size_t)NBA * HID * 4);
    float* Qb     = (float*)alloc((size_t)NHEAD * NBA * HID * 4);
    float* Kb     = (float*)alloc((size_t)NHEAD * NBA * HID * 4);
    float* Vb     = (float*)alloc((size_t)NHEAD * NBA * HID * 4);
    float* sHmB   = (float*)alloc((size_t)NHEAD * NBA * HID * 4);
    float* t1s    = (float*)alloc((size_t)NHEAD * NBA * HID * 4);
    float* t2b    = (float*)alloc((size_t)NHEAD * NBA * HID * 4);

    k_extract<<<NBA, 64, 0, stream>>>(x, idxb, valb, nval);

    k_encode<<<NBA * EMAX / 16, 256, 0, stream>>>(idxb, valb, nval, fourB,
                                                  enc_W1, enc_b1, enc_W2, enc_b2,
                                                  pad_tok, e);

    // compression: h1 = e @ comp_W1^T  (M=3200, N=512, K=25600), split-K 4
    k_gemm128<0, true><<<dim3(4, 25, 4), 256, 0, stream>>>(
        e, comp_W1, nullptr, g3part, NBA, 512, EMAX * HID, 0, 0, 0, 0, 6400);
    k_g3red<<<NBA * 512 / 1024, 256, 0, stream>>>(g3part, comp_b1, h1s);
    k_gemm128<0, false><<<dim3(2, 25, 1), 256, 0, stream>>>(
        h1s, comp_W2, comp_b2, h, NBA, HID, 512, 0, 0, 0, 0, 0);

    const long long sW = (long long)HID * HID;   // 65536
    const long long sC = (long long)NBA * HID;   // 819200
    for (int step = 0; step < 3; ++step) {
        k_gemm128<0, false><<<dim3(2, 25, 4), 256, 0, stream>>>(
            h, qW, nullptr, Qb, NBA, HID, HID, 0, sW, 0, sC, 0);
        k_gemm128<0, false><<<dim3(2, 25, 4), 256, 0, stream>>>(
            h, kW, nullptr, Kb, NBA, HID, HID, 0, sW, 0, sC, 0);
        k_gemm128<0, false><<<dim3(2, 25, 4), 256, 0, stream>>>(
            h, vW, nullptr, Vb, NBA, HID, HID, 0, sW, 0, sC, 0);
        k_attn<<<dim3(2, NBATCH, NHEAD), 256, 0, stream>>>(Qb, Kb, Vb, conn, sHmB);
        k_gemm128<1, false><<<dim3(2, 25, 4), 256, 0, stream>>>(
            sHmB, fpW1, fpb1, t1s, NBA, HID, HID, sC, sW, HID, sC, 0);
        k_gemm128<0, false><<<dim3(2, 25, 4), 256, 0, stream>>>(
            t1s, fpW2, fpb2, t2b, NBA, HID, HID, sC, sW, HID, sC, 0);
        k_ln_mean<<<NBA, 256, 0, stream>>>(t2b, ln_g, ln_b, h);
    }

    // out = h @ out_W^T + out_b  (M=3200, N=10000, K=256)
    k_gemm128<0, false><<<dim3(79, 25, 1), 256, 0, stream>>>(
        h, out_W, out_b, outp, NBA, NOUT, HID, 0, 0, 0, 0, 0);

    (void)in_sizes; (void)n_in; (void)out_size; (void)ws_size;
}

// Round 2
// 2546.242 us; speedup vs baseline: 1.6993x; 1.6993x over previous
//
#include <hip/hip_runtime.h>
#include <cstdint>
#include <cstddef>

#define NBATCH 32
#define NAGENT 100
#define NDIM   10000
#define HID    256
#define NHEAD  4
#define NOUT   10000
#define NFREQ  16
#define EMAX   100
#define NBA    3200                        // NBATCH * NAGENT
#define KBIG   25600                       // EMAX * HID
#define TWO_PI 6.283185307179586476925f

typedef float  v4f  __attribute__((ext_vector_type(4)));
typedef short  v8s  __attribute__((ext_vector_type(8)));

__device__ __forceinline__ unsigned short bf_hi(float f) {
    unsigned int u = __float_as_uint(f);
    return (unsigned short)((u + 0x7FFFu + ((u >> 16) & 1u)) >> 16);
}
__device__ __forceinline__ float bf_tof(unsigned short h) {
    return __uint_as_float(((unsigned int)h) << 16);
}

// ---------------------------------------------------------------------------
// Stage 1: per-(b,a) stream compaction of nonzeros (ascending flat index),
// truncated to EMAX. One wave per (b,a). Matches stable argsort order.
// ---------------------------------------------------------------------------
__global__ __launch_bounds__(64) void k_extract(const float* __restrict__ x,
                                                int* __restrict__ idxb,
                                                float* __restrict__ valb,
                                                int* __restrict__ nvalid)
{
    const int ba = blockIdx.x;
    const float* xr = x + (size_t)ba * NDIM;
    const int lane = threadIdx.x;
    int base = 0;
    for (int c0 = 0; c0 < NDIM; c0 += 64) {
        int i = c0 + lane;
        float v = (i < NDIM) ? xr[i] : 0.0f;
        unsigned long long m = __ballot(v != 0.0f);
        if (v != 0.0f) {
            int p = base + __popcll(m & ((1ull << lane) - 1ull));
            if (p < EMAX) {
                idxb[(size_t)ba * EMAX + p] = i;
                valb[(size_t)ba * EMAX + p] = v;
            }
        }
        base += __popcll(m);
        if (base >= EMAX) break;           // uniform across wave
    }
    if (lane == 0) nvalid[ba] = base < EMAX ? base : EMAX;
}

// ---------------------------------------------------------------------------
// Stage 2: fourier + encoder layer-1 only. g1 = swish(feat @ enc_W1^T + b1),
// zeroed for invalid slots; written as bf16 hi/lo pair (exact to ~2^-17).
// Layer-2 (enc_W2) is folded into comp_W1 algebraically (see k_tables/W1p).
// ---------------------------------------------------------------------------
__global__ __launch_bounds__(256) void k_g1(
    const int* __restrict__ idxb, const float* __restrict__ valb,
    const int* __restrict__ nvalid, const float* __restrict__ fourB,
    const float* __restrict__ W1, const float* __restrict__ b1,
    unsigned short* __restrict__ g1h, unsigned short* __restrict__ g1l)
{
    __shared__ float s_feat[16][36];
    __shared__ float s_w[8448];            // enc_W1 256x33
    __shared__ float s_b1v[256];
    __shared__ int   s_idx[16];
    __shared__ int   s_valid[16];

    const int t  = threadIdx.x;
    const int g0 = blockIdx.x * 16;

    if (t < 16) {
        int g = g0 + t;
        int ba = g / 100, slot = g - ba * 100;
        int valid = (slot < nvalid[ba]) ? 1 : 0;
        s_valid[t]   = valid;
        s_idx[t]     = valid ? idxb[g] : 0;
        s_feat[t][0] = valid ? valb[g] : 0.0f;
    }
    s_b1v[t] = b1[t];
    for (int i = t; i < 8448; i += 256) s_w[i] = W1[i];
    __syncthreads();

    {   // Fourier features: 16 entries x 16 freqs = 256 work items
        int ent = t >> 4, f = t & 15;
        float sv = 0.0f, cv = 0.0f;
        if (s_valid[ent]) {
            int id = s_idx[ent];
            float row = (float)(id / 100);
            float col = (float)(id % 100);
            float pr = TWO_PI * (row * fourB[2 * f] + col * fourB[2 * f + 1]);
            sv = sinf(pr); cv = cosf(pr);
        }
        s_feat[ent][1 + f]  = sv;
        s_feat[ent][17 + f] = cv;
    }
    __syncthreads();

    const float* wr = &s_w[t * 33];        // stride 33: conflict-free (33%32==1)
    for (int ent = 0; ent < 16; ++ent) {
        float a = s_b1v[t];
        #pragma unroll
        for (int c = 0; c < 33; ++c) a += s_feat[ent][c] * wr[c];
        float g = a / (1.0f + expf(-a));   // swish
        g = s_valid[ent] ? g : 0.0f;
        unsigned short h = bf_hi(g);
        unsigned short l = bf_hi(g - bf_tof(h));
        size_t o = (size_t)(g0 + ent) * 256 + t;
        g1h[o] = h;
        g1l[o] = l;
    }
}

// ---------------------------------------------------------------------------
// W2T[k'][k] = W2[k][k']  (tiny, 256 KB)
// ---------------------------------------------------------------------------
__global__ void k_w2t(const float* __restrict__ W2, float* __restrict__ W2T)
{
    int kp = blockIdx.x, k = threadIdx.x;
    W2T[kp * 256 + k] = W2[k * 256 + kp];
}

// ---------------------------------------------------------------------------
// fp32 -> bf16 hi/lo elementwise split (for W1p)
// ---------------------------------------------------------------------------
__global__ __launch_bounds__(256) void k_wsplit(const float* __restrict__ src,
                                                unsigned short* __restrict__ hi,
                                                unsigned short* __restrict__ lo)
{
    int i = (blockIdx.x * 256 + threadIdx.x) * 4;
    float4 f = *(const float4*)(src + i);
    ushort4 h, l;
    h.x = bf_hi(f.x); l.x = bf_hi(f.x - bf_tof(h.x));
    h.y = bf_hi(f.y); l.y = bf_hi(f.y - bf_tof(h.y));
    h.z = bf_hi(f.z); l.z = bf_hi(f.z - bf_tof(h.z));
    h.w = bf_hi(f.w); l.w = bf_hi(f.w - bf_tof(h.w));
    *(ushort4*)(hi + i) = h;
    *(ushort4*)(lo + i) = l;
}

// ---------------------------------------------------------------------------
// Bias tables for the W2-fold:
//  D[slot][n]  = (pad - b2) . comp_W1[n, slot-block]     (suffix-summed later)
//  E0[n]       = sum_slot b2 . comp_W1[n, slot-block]
// One block per n (512 blocks, 256 threads), coalesced W1 reads.
// ---------------------------------------------------------------------------
__global__ __launch_bounds__(256) void k_tables(
    const float* __restrict__ W1, const float* __restrict__ pad,
    const float* __restrict__ b2, float* __restrict__ D, float* __restrict__ E0)
{
    __shared__ float red[4];
    const int n = blockIdx.x;
    const int t = threadIdx.x, lane = t & 63, w = t >> 6;
    const float pm = pad[t] - b2[t];
    const float bb = b2[t];
    const float* wr = W1 + (size_t)n * KBIG;
    float eb = 0.0f;
    for (int s = 0; s < 100; ++s) {
        float wv = wr[s * 256 + t];
        float p = pm * wv;
        eb += bb * wv;
        #pragma unroll
        for (int o = 32; o > 0; o >>= 1) p += __shfl_down(p, o);
        if (lane == 0) red[w] = p;
        __syncthreads();
        if (t == 0) D[s * 512 + n] = red[0] + red[1] + red[2] + red[3];
        __syncthreads();
    }
    #pragma unroll
    for (int o = 32; o > 0; o >>= 1) eb += __shfl_down(eb, o);
    if (lane == 0) red[w] = eb;
    __syncthreads();
    if (t == 0) E0[n] = red[0] + red[1] + red[2] + red[3];
}

__global__ void k_suffix(const float* __restrict__ D, float* __restrict__ Corr)
{
    int n = blockIdx.x * 256 + threadIdx.x;   // 512 columns
    float c = 0.0f;
    Corr[100 * 512 + n] = 0.0f;
    for (int s = 99; s >= 0; --s) { c += D[s * 512 + n]; Corr[s * 512 + n] = c; }
}

// ---------------------------------------------------------------------------
// Generic fp32 GEMM: C = act(A @ W^T + bias).  128x128 tile, BK=16, 8x8 micro.
// z = batch index with element strides sA/sW/sBias/sC.
// ---------------------------------------------------------------------------
template<int ACT>
__global__ __launch_bounds__(256) void k_gemm128(
    const float* __restrict__ A, const float* __restrict__ W,
    const float* __restrict__ bias, float* __restrict__ C,
    int M, int N, int K,
    long long sA, long long sW, long long sBias, long long sC)
{
    __shared__ float As[16][132];
    __shared__ float Ws[16][132];
    const int t = threadIdx.x;
    const int z = blockIdx.z;
    A += (size_t)z * sA;
    W += (size_t)z * sW;
    C += (size_t)z * sC;
    if (bias) bias += (size_t)z * sBias;
    const int bm = blockIdx.y * 128, bn = blockIdx.x * 128;
    const int m0 = (t & 15) * 8, n0 = (t >> 4) * 8;

    float acc[8][8];
    #pragma unroll
    for (int i = 0; i < 8; ++i)
        #pragma unroll
        for (int j = 0; j < 8; ++j) acc[i][j] = 0.0f;

    float4 av[2], wv[2];
    #pragma unroll
    for (int i = 0; i < 2; ++i) {
        int id = i * 256 + t;
        int row = id >> 2;
        int kg = (id & 3) << 2;
        av[i] = *(const float4*)(A + (size_t)(bm + row) * K + kg);
        int nr = bn + row;
        wv[i] = (nr < N) ? *(const float4*)(W + (size_t)nr * K + kg)
                         : make_float4(0.f, 0.f, 0.f, 0.f);
    }

    for (int k0 = 0; k0 < K; k0 += 16) {
        __syncthreads();
        #pragma unroll
        for (int i = 0; i < 2; ++i) {
            int id = i * 256 + t;
            int row = id >> 2;
            int kg = (id & 3) << 2;
            As[kg + 0][row] = av[i].x; As[kg + 1][row] = av[i].y;
            As[kg + 2][row] = av[i].z; As[kg + 3][row] = av[i].w;
            Ws[kg + 0][row] = wv[i].x; Ws[kg + 1][row] = wv[i].y;
            Ws[kg + 2][row] = wv[i].z; Ws[kg + 3][row] = wv[i].w;
        }
        __syncthreads();
        int kn = k0 + 16;
        if (kn < K) {
            #pragma unroll
            for (int i = 0; i < 2; ++i) {
                int id = i * 256 + t;
                int row = id >> 2;
                int kg = (id & 3) << 2;
                av[i] = *(const float4*)(A + (size_t)(bm + row) * K + kn + kg);
                int nr = bn + row;
                wv[i] = (nr < N) ? *(const float4*)(W + (size_t)nr * K + kn + kg)
                                 : make_float4(0.f, 0.f, 0.f, 0.f);
            }
        }
        #pragma unroll
        for (int kk = 0; kk < 16; ++kk) {
            float a[8], w[8];
            *(float4*)&a[0] = *(const float4*)&As[kk][m0];
            *(float4*)&a[4] = *(const float4*)&As[kk][m0 + 4];
            *(float4*)&w[0] = *(const float4*)&Ws[kk][n0];
            *(float4*)&w[4] = *(const float4*)&Ws[kk][n0 + 4];
            #pragma unroll
            for (int i = 0; i < 8; ++i)
                #pragma unroll
                for (int j = 0; j < 8; ++j)
                    acc[i][j] += a[i] * w[j];
        }
    }

    #pragma unroll
    for (int i = 0; i < 8; ++i) {
        int row = bm + m0 + i;
        float* crow = C + (size_t)row * N;
        #pragma unroll
        for (int j = 0; j < 8; ++j) {
            int n = bn + n0 + j;
            if (n < N) {
                float v = acc[i][j];
                if (bias) v += bias[n];
                if (ACT == 1) v = v / (1.0f + expf(-v));   // swish
                crow[n] = v;
            }
        }
    }
}

// ---------------------------------------------------------------------------
// Compression GEMM via bf16 MFMA with hi/lo split (fp32-grade accuracy):
// part[z] += (Ah+Al) @ (Wh+Wl)^T  over K-chunk z (3 MFMAs: hh, hl, lh).
// A: g1 [3200][25600] bf16 hi/lo, W: W1p [512][25600] bf16 hi/lo.
// 128x128 tile, BK=32, 4 waves each 64x64 (4x4 of 16x16x32 MFMA tiles).
// Fragment layouts per m89/m74-verified mapping.
// ---------------------------------------------------------------------------
__global__ __launch_bounds__(256) void k_g3mfma(
    const unsigned short* __restrict__ Ah, const unsigned short* __restrict__ Al,
    const unsigned short* __restrict__ Wh, const unsigned short* __restrict__ Wl,
    float* __restrict__ part)
{
    __shared__ unsigned short sAh[4096], sAl[4096], sWh[4096], sWl[4096];
    const int t  = threadIdx.x;
    const int bn = blockIdx.x * 128;       // N in [0,512)
    const int bm = blockIdx.y * 128;       // M in [0,3200)
    const int z  = blockIdx.z;             // split-K chunk, 8 x 3200
    const int lane = t & 63, w = t >> 6;
    const int wm = (w & 1) * 64, wn = (w >> 1) * 64;
    const size_t K = KBIG;
    const int r0 = t >> 2, kq = (t & 3) * 8;   // uint4 j=t: row=t>>2, k-oct
    const int r1 = 64 + r0;                    // uint4 j=t+256

    const unsigned short* pA0 = Ah + (size_t)(bm + r0) * K + z * 3200 + kq;
    const unsigned short* pA1 = Ah + (size_t)(bm + r1) * K + z * 3200 + kq;
    const unsigned short* pa0 = Al + (size_t)(bm + r0) * K + z * 3200 + kq;
    const unsigned short* pa1 = Al + (size_t)(bm + r1) * K + z * 3200 + kq;
    const unsigned short* pW0 = Wh + (size_t)(bn + r0) * K + z * 3200 + kq;
    const unsigned short* pW1 = Wh + (size_t)(bn + r1) * K + z * 3200 + kq;
    const unsigned short* pw0 = Wl + (size_t)(bn + r0) * K + z * 3200 + kq;
    const unsigned short* pw1 = Wl + (size_t)(bn + r1) * K + z * 3200 + kq;

    uint4 rA0 = *(const uint4*)pA0, rA1 = *(const uint4*)pA1;
    uint4 ra0 = *(const uint4*)pa0, ra1 = *(const uint4*)pa1;
    uint4 rW0 = *(const uint4*)pW0, rW1 = *(const uint4*)pW1;
    uint4 rw0 = *(const uint4*)pw0, rw1 = *(const uint4*)pw1;

    v4f acc[4][4] = {};

    for (int kt = 0; kt < 100; ++kt) {
        __syncthreads();
        *(uint4*)&sAh[r0 * 32 + kq] = rA0;  *(uint4*)&sAh[r1 * 32 + kq] = rA1;
        *(uint4*)&sAl[r0 * 32 + kq] = ra0;  *(uint4*)&sAl[r1 * 32 + kq] = ra1;
        *(uint4*)&sWh[r0 * 32 + kq] = rW0;  *(uint4*)&sWh[r1 * 32 + kq] = rW1;
        *(uint4*)&sWl[r0 * 32 + kq] = rw0;  *(uint4*)&sWl[r1 * 32 + kq] = rw1;
        __syncthreads();
        if (kt < 99) {
            int off = (kt + 1) * 32;
            rA0 = *(const uint4*)(pA0 + off);  rA1 = *(const uint4*)(pA1 + off);
            ra0 = *(const uint4*)(pa0 + off);  ra1 = *(const uint4*)(pa1 + off);
            rW0 = *(const uint4*)(pW0 + off);  rW1 = *(const uint4*)(pW1 + off);
            rw0 = *(const uint4*)(pw0 + off);  rw1 = *(const uint4*)(pw1 + off);
        }
        const int fr = lane & 15, fq = (lane >> 4) * 8;
        v8s ah[4], al[4], bh[4], bl[4];
        #pragma unroll
        for (int i = 0; i < 4; ++i) {
            ah[i] = *(const v8s*)&sAh[(wm + i * 16 + fr) * 32 + fq];
            al[i] = *(const v8s*)&sAl[(wm + i * 16 + fr) * 32 + fq];
            bh[i] = *(const v8s*)&sWh[(wn + i * 16 + fr) * 32 + fq];
            bl[i] = *(const v8s*)&sWl[(wn + i * 16 + fr) * 32 + fq];
        }
        #pragma unroll
        for (int mi = 0; mi < 4; ++mi)
            #pragma unroll
            for (int ni = 0; ni < 4; ++ni) {
                acc[mi][ni] = __builtin_amdgcn_mfma_f32_16x16x32_bf16(ah[mi], bh[ni], acc[mi][ni], 0, 0, 0);
                acc[mi][ni] = __builtin_amdgcn_mfma_f32_16x16x32_bf16(ah[mi], bl[ni], acc[mi][ni], 0, 0, 0);
                acc[mi][ni] = __builtin_amdgcn_mfma_f32_16x16x32_bf16(al[mi], bh[ni], acc[mi][ni], 0, 0, 0);
            }
    }

    const int er = (lane >> 4) * 4, ec = lane & 15;  // C/D: col=lane&15, row=quad*4+reg
    float* cp = part + (size_t)z * NBA * 512;
    #pragma unroll
    for (int mi = 0; mi < 4; ++mi)
        #pragma unroll
        for (int ni = 0; ni < 4; ++ni) {
            int m = bm + wm + mi * 16 + er;
            int n = bn + wn + ni * 16 + ec;
            #pragma unroll
            for (int r = 0; r < 4; ++r)
                cp[(size_t)(m + r) * 512 + n] = acc[mi][ni][r];
        }
}

// ---------------------------------------------------------------------------
// Split-K reduce + fold-bias + swish:
// h1s = swish(sum_z part + comp_b1 + E0 + Corr[nvalid[ba]])
// ---------------------------------------------------------------------------
__global__ __launch_bounds__(256) void k_g3red(
    const float* __restrict__ part, const float* __restrict__ comp_b1,
    const float* __restrict__ E0, const float* __restrict__ Corr,
    const int* __restrict__ nvalid, float* __restrict__ h1s)
{
    const int i4 = (blockIdx.x * 256 + threadIdx.x) * 4;
    const int ba = i4 >> 9, n = i4 & 511;
    const size_t S = (size_t)NBA * 512;
    float4 s = *(const float4*)(part + i4);
    #pragma unroll
    for (int zz = 1; zz < 8; ++zz) {
        float4 p = *(const float4*)(part + zz * S + i4);
        s.x += p.x; s.y += p.y; s.z += p.z; s.w += p.w;
    }
    int nv = nvalid[ba];
    float4 b  = *(const float4*)(comp_b1 + n);
    float4 e  = *(const float4*)(E0 + n);
    float4 c  = *(const float4*)(Corr + nv * 512 + n);
    float r0 = s.x + b.x + e.x + c.x;
    float r1 = s.y + b.y + e.y + c.y;
    float r2 = s.z + b.z + e.z + c.z;
    float r3 = s.w + b.w + e.w + c.w;
    float4 o;
    o.x = r0 / (1.0f + expf(-r0));
    o.y = r1 / (1.0f + expf(-r1));
    o.z = r2 / (1.0f + expf(-r2));
    o.w = r3 / (1.0f + expf(-r3));
    *(float4*)(h1s + i4) = o;
}

// ---------------------------------------------------------------------------
// Fused attention (unchanged from R1; output buffer aliases Qb — each block
// reads only its own half's Q rows before writing those same rows).
// ---------------------------------------------------------------------------
__global__ __launch_bounds__(256) void k_attn(
    const float* __restrict__ Qb, const float* __restrict__ Kb,
    const float* __restrict__ Vb, const float* __restrict__ conn,
    float* __restrict__ sHm)
{
    __shared__ float sKV[256][101];
    __shared__ float sAl[50][100];
    __shared__ float sQ[2][256];
    __shared__ float sRed[2][2];

    const int t = threadIdx.x;
    const int half = blockIdx.x, b = blockIdx.y, n = blockIdx.z;
    const size_t base = ((size_t)n * NBA + b * 100) * 256;

    const float* Kp = Kb + base;
    for (int r = 0; r < 100; ++r) sKV[t][r] = Kp[(size_t)r * 256 + t];
    __syncthreads();

    const float* Qp = Qb + base;
    const int pair = t >> 7, tt = t & 127, lane = t & 63, wvi = t >> 6;

    for (int rr = 0; rr < 25; ++rr) {
        const int row0 = half * 50 + rr * 2;
        const int lr = rr * 2 + pair;
        __syncthreads();
        sQ[0][t] = Qp[(size_t)(row0)*256 + t];
        sQ[1][t] = Qp[(size_t)(row0 + 1) * 256 + t];
        __syncthreads();
        float sc = 0.0f;
        if (tt < 100) {
            const float* qr = sQ[pair];
            float p0 = 0.f, p1 = 0.f, p2 = 0.f, p3 = 0.f;
            #pragma unroll 4
            for (int c = 0; c < 256; c += 4) {
                p0 += qr[c]     * sKV[c][tt];
                p1 += qr[c + 1] * sKV[c + 1][tt];
                p2 += qr[c + 2] * sKV[c + 2][tt];
                p3 += qr[c + 3] * sKV[c + 3][tt];
            }
            sc = ((p0 + p1) + (p2 + p3)) * 0.0625f + conn[(row0 + pair) * 100 + tt];
            sAl[lr][tt] = sc;
        }
        __syncthreads();
        if ((wvi & 1) == 0) {
            int p = wvi >> 1;
            int r2 = rr * 2 + p;
            float m = sAl[r2][lane];
            if (lane < 36) m = fmaxf(m, sAl[r2][lane + 64]);
            #pragma unroll
            for (int off = 32; off > 0; off >>= 1)
                m = fmaxf(m, __shfl_down(m, off));
            if (lane == 0) sRed[0][p] = m;
        }
        __syncthreads();
        float ex = 0.0f;
        if (tt < 100) {
            ex = expf(sc - sRed[0][pair]);
            sAl[lr][tt] = ex;
        }
        __syncthreads();
        if ((wvi & 1) == 0) {
            int p = wvi >> 1;
            int r2 = rr * 2 + p;
            float s = sAl[r2][lane];
            if (lane < 36) s += sAl[r2][lane + 64];
            #pragma unroll
            for (int off = 32; off > 0; off >>= 1)
                s += __shfl_down(s, off);
            if (lane == 0) sRed[1][p] = s;
        }
        __syncthreads();
        if (tt < 100) sAl[lr][tt] = ex / sRed[1][pair];
    }
    __syncthreads();

    const float* Vp = Vb + base;
    for (int r = 0; r < 100; ++r) sKV[t][r] = Vp[(size_t)r * 256 + t];
    __syncthreads();

    float* Op = sHm + base;
    for (int rr = 0; rr < 50; ++rr) {
        int row = half * 50 + rr;
        float a = 0.0f;
        #pragma unroll 4
        for (int j = 0; j < 100; ++j) a += sAl[rr][j] * sKV[t][j];
        float sw = a / (1.0f + expf(-a));   // swish fused (fp1 consumes swish(Hm))
        Op[(size_t)row * 256 + t] = sw;
    }
}

// ---------------------------------------------------------------------------
// Per-head layernorm over HID + mean over heads -> new h.
// ---------------------------------------------------------------------------
__global__ __launch_bounds__(256) void k_ln_mean(
    const float* __restrict__ t2b, const float* __restrict__ ln_g,
    const float* __restrict__ ln_b, float* __restrict__ h)
{
    __shared__ float so[4][256];
    const int ba = blockIdx.x, t = threadIdx.x;
    const int n = t >> 6, lane = t & 63;
    const float* tr = t2b + ((size_t)n * NBA + ba) * HID;
    float4 v = *(const float4*)(tr + lane * 4);
    float s1 = v.x + v.y + v.z + v.w;
    float s2 = v.x * v.x + v.y * v.y + v.z * v.z + v.w * v.w;
    #pragma unroll
    for (int off = 32; off > 0; off >>= 1) {
        s1 += __shfl_down(s1, off);
        s2 += __shfl_down(s2, off);
    }
    s1 = __shfl(s1, 0);
    s2 = __shfl(s2, 0);
    float m = s1 * (1.0f / 256.0f);
    float var = s2 * (1.0f / 256.0f) - m * m;
    float rstd = 1.0f / sqrtf(var + 1e-5f);
    float4 gv = *(const float4*)(ln_g + n * HID + lane * 4);
    float4 bv = *(const float4*)(ln_b + n * HID + lane * 4);
    float4 o;
    o.x = (v.x - m) * rstd * gv.x + bv.x;
    o.y = (v.y - m) * rstd * gv.y + bv.y;
    o.z = (v.z - m) * rstd * gv.z + bv.z;
    o.w = (v.w - m) * rstd * gv.w + bv.w;
    *(float4*)&so[n][lane * 4] = o;
    __syncthreads();
    h[(size_t)ba * HID + t] = 0.25f * (so[0][t] + so[1][t] + so[2][t] + so[3][t]);
}

// ---------------------------------------------------------------------------
extern "C" void kernel_launch(void* const* d_in, const int* in_sizes, int n_in,
                              void* d_out, int out_size, void* d_ws, size_t ws_size,
                              hipStream_t stream)
{
    const float* x       = (const float*)d_in[0];
    const float* fourB   = (const float*)d_in[1];
    const float* enc_W1  = (const float*)d_in[2];
    const float* enc_b1  = (const float*)d_in[3];
    const float* enc_W2  = (const float*)d_in[4];
    const float* enc_b2  = (const float*)d_in[5];
    const float* pad_tok = (const float*)d_in[6];
    const float* comp_W1 = (const float*)d_in[7];
    const float* comp_b1 = (const float*)d_in[8];
    const float* comp_W2 = (const float*)d_in[9];
    const float* comp_b2 = (const float*)d_in[10];
    const float* conn    = (const float*)d_in[11];
    const float* qW      = (const float*)d_in[12];
    const float* kW      = (const float*)d_in[13];
    const float* vW      = (const float*)d_in[14];
    const float* fpW1    = (const float*)d_in[15];
    const float* fpb1    = (const float*)d_in[16];
    const float* fpW2    = (const float*)d_in[17];
    const float* fpb2    = (const float*)d_in[18];
    const float* ln_g    = (const float*)d_in[19];
    const float* ln_b    = (const float*)d_in[20];
    const float* out_W   = (const float*)d_in[21];
    const float* out_b   = (const float*)d_in[22];
    float* outp = (float*)d_out;

    char* ws = (char*)d_ws;
    size_t off = 0;
    auto alloc = [&](size_t bytes) -> void* {
        void* p = (void*)(ws + off);
        off += (bytes + 255) & ~(size_t)255;
        return p;
    };
    int*   idxb = (int*)  alloc((size_t)NBA * EMAX * 4);
    float* valb = (float*)alloc((size_t)NBA * EMAX * 4);
    int*   nval = (int*)  alloc((size_t)NBA * 4);
    unsigned short* g1h = (unsigned short*)alloc((size_t)NBA * KBIG * 2);  // 163.8 MB
    unsigned short* g1l = (unsigned short*)alloc((size_t)NBA * KBIG * 2);  // 163.8 MB
    float* W2T  = (float*)alloc((size_t)256 * 256 * 4);
    float* W1p  = (float*)alloc((size_t)512 * KBIG * 4);     // 52.4 MB; reused as split-K partials
    float* part = W1p;                                       // alias (W1p dead after k_wsplit)
    unsigned short* Whi = (unsigned short*)alloc((size_t)512 * KBIG * 2);
    unsigned short* Wlo = (unsigned short*)alloc((size_t)512 * KBIG * 2);
    float* Dt   = (float*)alloc((size_t)100 * 512 * 4);
    float* Corr = (float*)alloc((size_t)101 * 512 * 4);
    float* E0   = (float*)alloc((size_t)512 * 4);
    float* h1s  = (float*)alloc((size_t)NBA * 512 * 4);
    float* h    = (float*)alloc((size_t)NBA * HID * 4);
    float* Qb   = (float*)alloc((size_t)NHEAD * NBA * HID * 4);
    float* Kb   = (float*)alloc((size_t)NHEAD * NBA * HID * 4);
    float* Vb   = (float*)alloc((size_t)NHEAD * NBA * HID * 4);
    float* Wqkv = (float*)alloc((size_t)3 * NHEAD * HID * HID * 4);
    // aliases (lifetimes disjoint within a step)
    float* sHmB = Qb;   // attn writes its own half's rows after reading them
    float* t1s  = Kb;   // K dead after attn
    float* t2b  = Vb;   // V dead after attn

    const long long sW = (long long)HID * HID;   // 65536
    const long long sC = (long long)NBA * HID;   // 819200

    k_extract<<<NBA, 64, 0, stream>>>(x, idxb, valb, nval);
    k_g1<<<NBA * EMAX / 16, 256, 0, stream>>>(idxb, valb, nval, fourB,
                                              enc_W1, enc_b1, g1h, g1l);

    // fold enc_W2 into comp_W1:  W1p[(n,slot)][k'] = sum_k W1[n,slot,k]*W2[k][k']
    k_w2t<<<256, 256, 0, stream>>>(enc_W2, W2T);
    k_gemm128<0><<<dim3(2, 400, 1), 256, 0, stream>>>(
        comp_W1, W2T, nullptr, W1p, 512 * EMAX, 256, 256, 0, 0, 0, 0);
    k_wsplit<<<512 * KBIG / 1024, 256, 0, stream>>>(W1p, Whi, Wlo);
    k_tables<<<512, 256, 0, stream>>>(comp_W1, pad_tok, enc_b2, Dt, E0);
    k_suffix<<<2, 256, 0, stream>>>(Dt, Corr);

    // concat QKV weights once per call (harness re-poisons ws every call)
    hipMemcpyAsync(Wqkv,                 qW, (size_t)NHEAD * sW * 4, hipMemcpyDeviceToDevice, stream);
    hipMemcpyAsync(Wqkv + NHEAD * sW,    kW, (size_t)NHEAD * sW * 4, hipMemcpyDeviceToDevice, stream);
    hipMemcpyAsync(Wqkv + 2 * NHEAD * sW, vW, (size_t)NHEAD * sW * 4, hipMemcpyDeviceToDevice, stream);

    // compression GEMM (M=3200,N=512,K=25600) in split-bf16 MFMA, split-K=8
    k_g3mfma<<<dim3(4, 25, 8), 256, 0, stream>>>(g1h, g1l, Whi, Wlo, part);
    k_g3red<<<NBA * 512 / 1024, 256, 0, stream>>>(part, comp_b1, E0, Corr, nval, h1s);
    k_gemm128<0><<<dim3(2, 25, 1), 256, 0, stream>>>(
        h1s, comp_W2, comp_b2, h, NBA, HID, 512, 0, 0, 0, 0);

    for (int step = 0; step < 3; ++step) {
        k_gemm128<0><<<dim3(2, 25, 12), 256, 0, stream>>>(
            h, Wqkv, nullptr, Qb, NBA, HID, HID, 0, sW, 0, sC);
        k_attn<<<dim3(2, NBATCH, NHEAD), 256, 0, stream>>>(Qb, Kb, Vb, conn, sHmB);
        k_gemm128<1><<<dim3(2, 25, 4), 256, 0, stream>>>(
            sHmB, fpW1, fpb1, t1s, NBA, HID, HID, sC, sW, HID, sC);
        k_gemm128<0><<<dim3(2, 25, 4), 256, 0, stream>>>(
            t1s, fpW2, fpb2, t2b, NBA, HID, HID, sC, sW, HID, sC);
        k_ln_mean<<<NBA, 256, 0, stream>>>(t2b, ln_g, ln_b, h);
    }

    // out = h @ out_W^T + out_b  (M=3200, N=10000, K=256)
    k_gemm128<0><<<dim3(79, 25, 1), 256, 0, stream>>>(
        h, out_W, out_b, outp, NBA, NOUT, HID, 0, 0, 0, 0);

    (void)in_sizes; (void)n_in; (void)out_size; (void)ws_size;
}